// Round 1
// baseline (96966.516 us; speedup 1.0000x reference)
//
#include <hip/hip_runtime.h>
#include <math.h>

#define S 512
#define B 64
#define D 64
#define H 1024
#define L 128
#define G4 4096

#define NWG 512
#define TPB 256

// ---- workspace layout (in floats) ----
#define OFF_CNT   0                       // 64 floats reserved (2 counters, separate lines)
#define OFF_HBUF  64                      // 2 * H * B
#define OFF_XT    (OFF_HBUF + 2*H*B)      // S*D*B
#define OFF_WCOMB (OFF_XT + S*D*B)        // G4*H
#define OFF_BCOMB (OFF_WCOMB + (size_t)G4*H)  // G4
#define OFF_OUTWT (OFF_BCOMB + G4)        // H*D
#define OFF_LAT   (OFF_OUTWT + H*D)       // L*B

__device__ __forceinline__ float sigmoidf_(float x) {
  return 1.f / (1.f + __expf(-x));
}

// Grid barrier: monotonic counter, no reset. All NWG blocks co-resident.
__device__ __forceinline__ void gridbar(unsigned* cnt, unsigned target) {
  __syncthreads();
  if (threadIdx.x == 0) {
    __hip_atomic_fetch_add(cnt, 1u, __ATOMIC_RELEASE, __HIP_MEMORY_SCOPE_AGENT);
    while (__hip_atomic_load(cnt, __ATOMIC_RELAXED, __HIP_MEMORY_SCOPE_AGENT) < target) {
      __builtin_amdgcn_s_sleep(2);
    }
    __builtin_amdgcn_fence(__ATOMIC_ACQUIRE, "agent");
  }
  __syncthreads();
}

// x [B][S][D] -> xT [S][D][B]
__global__ __launch_bounds__(256) void k_transpose_x(const float* __restrict__ x,
                                                     float* __restrict__ xT) {
  __shared__ float tile[64][65];
  const int t = blockIdx.x;
  const int c = threadIdx.x & 63;
  const int r4 = threadIdx.x >> 6;
  #pragma unroll
  for (int i = 0; i < 16; ++i) {
    int b = r4 * 16 + i;
    tile[b][c] = x[((size_t)b * S + t) * D + c];
  }
  __syncthreads();
  #pragma unroll
  for (int i = 0; i < 16; ++i) {
    int d = r4 * 16 + i;
    xT[((size_t)t * D + d) * B + c] = tile[c][d];
  }
}

// Wcomb[r][k] = dec_Whh[r][k] + sum_d dec_Wih[r][d]*outW[d][k]
__global__ __launch_bounds__(256) void k_wcomb(const float* __restrict__ dWhh,
                                               const float* __restrict__ dWih,
                                               const float* __restrict__ outW,
                                               float* __restrict__ Wcomb) {
  const int r = blockIdx.x;
  const float* wih = dWih + (size_t)r * D;
  for (int kc = 0; kc < 4; ++kc) {
    int k = kc * 256 + threadIdx.x;
    float acc = dWhh[(size_t)r * H + k];
    #pragma unroll 8
    for (int d = 0; d < D; ++d) acc = fmaf(wih[d], outW[(size_t)d * H + k], acc);
    Wcomb[(size_t)r * H + k] = acc;
  }
}

// bcomb[r] = dec_b[r] + sum_d dec_Wih[r][d]*outb[d]
__global__ __launch_bounds__(256) void k_bcomb(const float* __restrict__ db,
                                               const float* __restrict__ dWih,
                                               const float* __restrict__ outb,
                                               float* __restrict__ bcomb) {
  int r = blockIdx.x * 256 + threadIdx.x;
  float acc = db[r];
  #pragma unroll 8
  for (int d = 0; d < D; ++d) acc = fmaf(dWih[(size_t)r * D + d], outb[d], acc);
  bcomb[r] = acc;
}

// outW [D][H] -> outWT [H][D]
__global__ __launch_bounds__(256) void k_outwt(const float* __restrict__ outW,
                                               float* __restrict__ outWT) {
  int idx = blockIdx.x * 256 + threadIdx.x;  // 65536
  int k = idx >> 6, d = idx & 63;
  outWT[idx] = outW[(size_t)d * H + k];
}

// Persistent encoder: 512 WGs x 256 thr. WG w owns j in {2w, 2w+1}.
// wave wv: jj = wv>>1, gate-pair q0 = (wv&1)*2. lane = b.
__global__ __launch_bounds__(TPB, 2) void k_encoder(
    const float* __restrict__ xT, const float* __restrict__ Wih,
    const float* __restrict__ Whh, const float* __restrict__ b4,
    float* __restrict__ hbuf, unsigned* __restrict__ cnt)
{
  const int lane = threadIdx.x & 63;
  const int wv = threadIdx.x >> 6;
  const int jj = wv >> 1;
  const int q0 = (wv & 1) << 1;
  const int j = (blockIdx.x << 1) + jj;
  const float* W0 = Whh + (size_t)(q0 * H + j) * H;
  const float* W1 = Whh + (size_t)((q0 + 1) * H + j) * H;
  const float* Wi0 = Wih + (size_t)(q0 * H + j) * D;
  const float* Wi1 = Wih + (size_t)((q0 + 1) * H + j) * D;
  const float bias0 = b4[q0 * H + j];
  const float bias1 = b4[(q0 + 1) * H + j];
  float c = 0.f;
  __shared__ float ex[2][2][64];

  for (int t = 0; t < S; ++t) {
    const float* hs = hbuf + (size_t)(t & 1) * (H * B) + lane;
    const float* xt = xT + (size_t)t * (D * B) + lane;
    float a0 = bias0, a1 = bias1;

    #pragma unroll
    for (int d = 0; d < D; d += 4) {
      float4 w0 = *(const float4*)(Wi0 + d);
      float4 w1 = *(const float4*)(Wi1 + d);
      float x0 = xt[(d + 0) * B], x1 = xt[(d + 1) * B];
      float x2 = xt[(d + 2) * B], x3 = xt[(d + 3) * B];
      a0 = fmaf(w0.x, x0, a0); a0 = fmaf(w0.y, x1, a0);
      a0 = fmaf(w0.z, x2, a0); a0 = fmaf(w0.w, x3, a0);
      a1 = fmaf(w1.x, x0, a1); a1 = fmaf(w1.y, x1, a1);
      a1 = fmaf(w1.z, x2, a1); a1 = fmaf(w1.w, x3, a1);
    }
    if (t > 0) {  // h == 0 at t = 0
      #pragma unroll 4
      for (int k = 0; k < H; k += 4) {
        float4 w0 = *(const float4*)(W0 + k);
        float4 w1 = *(const float4*)(W1 + k);
        float h0 = hs[(k + 0) * B], h1 = hs[(k + 1) * B];
        float h2 = hs[(k + 2) * B], h3 = hs[(k + 3) * B];
        a0 = fmaf(w0.x, h0, a0); a0 = fmaf(w0.y, h1, a0);
        a0 = fmaf(w0.z, h2, a0); a0 = fmaf(w0.w, h3, a0);
        a1 = fmaf(w1.x, h0, a1); a1 = fmaf(w1.y, h1, a1);
        a1 = fmaf(w1.z, h2, a1); a1 = fmaf(w1.w, h3, a1);
      }
    }
    // gates: q0==0 -> (i,f); q0==2 -> (g,o). Exchange g,o via LDS.
    if (wv & 1) { ex[jj][0][lane] = a0; ex[jj][1][lane] = a1; }
    __syncthreads();
    if (!(wv & 1)) {
      float ii = sigmoidf_(a0);
      float ff = sigmoidf_(a1);
      float gg = tanhf(ex[jj][0][lane]);
      float oo = sigmoidf_(ex[jj][1][lane]);
      c = fmaf(ff, c, ii * gg);
      float hnew = oo * tanhf(c);
      hbuf[(size_t)((t + 1) & 1) * (H * B) + j * B + lane] = hnew;
    }
    gridbar(cnt, (unsigned)(t + 1) * NWG);
  }
  // final h_enc sits in hbuf[0] (512 even)
}

// latent[l][b] = h_enc . enc_fcW[l] + enc_fcb[l]   (h_enc = hbuf[0], [k][b])
__global__ __launch_bounds__(256) void k_latent(const float* __restrict__ h0,
                                                const float* __restrict__ fcW,
                                                const float* __restrict__ fcb,
                                                float* __restrict__ latT) {
  const int l = blockIdx.x;
  const int b = threadIdx.x & 63;
  const int kq = threadIdx.x >> 6;
  float acc = 0.f;
  #pragma unroll 4
  for (int kk = 0; kk < 256; ++kk) {
    int k = kq * 256 + kk;
    acc = fmaf(h0[k * B + b], fcW[(size_t)l * H + k], acc);
  }
  __shared__ float red[4][64];
  red[kq][b] = acc;
  __syncthreads();
  if (kq == 0) latT[l * B + b] = red[0][b] + red[1][b] + red[2][b] + red[3][b] + fcb[l];
}

// h_dec[j][b] = latent . dec_fcW[j] + dec_fcb[j]  -> written into hbuf[0]
__global__ __launch_bounds__(256) void k_hdec(const float* __restrict__ latT,
                                              const float* __restrict__ fcW,
                                              const float* __restrict__ fcb,
                                              float* __restrict__ h0) {
  const int j = blockIdx.x;
  const int b = threadIdx.x & 63;
  const int kq = threadIdx.x >> 6;
  float acc = 0.f;
  #pragma unroll
  for (int kk = 0; kk < 32; ++kk) {
    int k = kq * 32 + kk;
    acc = fmaf(latT[k * B + b], fcW[(size_t)j * L + k], acc);
  }
  __shared__ float red[4][64];
  red[kq][b] = acc;
  __syncthreads();
  if (kq == 0) h0[j * B + b] = red[0][b] + red[1][b] + red[2][b] + red[3][b] + fcb[j];
}

// Persistent decoder. Step 0 uses dec_Whh/dec_b (xi=0); steps>=1 use Wcomb/bcomb
// (feedback folded in). After each barrier, WGs w<64 compute out[b=w][t][:].
__global__ __launch_bounds__(TPB, 2) void k_decoder(
    const float* __restrict__ dWhh, const float* __restrict__ db,
    const float* __restrict__ Wcomb, const float* __restrict__ bcomb,
    const float* __restrict__ outWT, const float* __restrict__ outb,
    float* __restrict__ hbuf, float* __restrict__ out, unsigned* __restrict__ cnt)
{
  const int lane = threadIdx.x & 63;
  const int wv = threadIdx.x >> 6;
  const int jj = wv >> 1;
  const int q0 = (wv & 1) << 1;
  const int j = (blockIdx.x << 1) + jj;
  const size_t row0 = (size_t)(q0 * H + j) * H;
  const size_t row1 = (size_t)((q0 + 1) * H + j) * H;
  const float bA0 = db[q0 * H + j],   bA1 = db[(q0 + 1) * H + j];
  const float bB0 = bcomb[q0 * H + j], bB1 = bcomb[(q0 + 1) * H + j];
  float c = 0.f;
  __shared__ float ex[2][2][64];
  __shared__ float red[4][64];
  const int w = blockIdx.x;

  for (int t = 0; t < S; ++t) {
    const float* Wb = (t == 0 ? dWhh : Wcomb);
    const float* W0 = Wb + row0;
    const float* W1 = Wb + row1;
    const float* hs = hbuf + (size_t)(t & 1) * (H * B) + lane;
    float a0 = (t == 0 ? bA0 : bB0);
    float a1 = (t == 0 ? bA1 : bB1);

    #pragma unroll 4
    for (int k = 0; k < H; k += 4) {
      float4 w0 = *(const float4*)(W0 + k);
      float4 w1 = *(const float4*)(W1 + k);
      float h0 = hs[(k + 0) * B], h1 = hs[(k + 1) * B];
      float h2 = hs[(k + 2) * B], h3 = hs[(k + 3) * B];
      a0 = fmaf(w0.x, h0, a0); a0 = fmaf(w0.y, h1, a0);
      a0 = fmaf(w0.z, h2, a0); a0 = fmaf(w0.w, h3, a0);
      a1 = fmaf(w1.x, h0, a1); a1 = fmaf(w1.y, h1, a1);
      a1 = fmaf(w1.z, h2, a1); a1 = fmaf(w1.w, h3, a1);
    }
    if (wv & 1) { ex[jj][0][lane] = a0; ex[jj][1][lane] = a1; }
    __syncthreads();
    if (!(wv & 1)) {
      float ii = sigmoidf_(a0);
      float ff = sigmoidf_(a1);
      float gg = tanhf(ex[jj][0][lane]);
      float oo = sigmoidf_(ex[jj][1][lane]);
      c = fmaf(ff, c, ii * gg);
      float hnew = oo * tanhf(c);
      hbuf[(size_t)((t + 1) & 1) * (H * B) + j * B + lane] = hnew;
    }
    gridbar(cnt, (unsigned)(t + 1) * NWG);

    if (w < B) {  // output projection for batch b = w, time t
      const float* hn = hbuf + (size_t)((t + 1) & 1) * (H * B);
      const int d = threadIdx.x & 63;
      const int kq = threadIdx.x >> 6;
      float acc = 0.f;
      #pragma unroll 4
      for (int kk = 0; kk < 256; ++kk) {
        int k = kq * 256 + kk;
        acc = fmaf(hn[k * B + w], outWT[k * B + d], acc);
      }
      red[kq][d] = acc;
      __syncthreads();
      if (kq == 0) {
        out[((size_t)w * S + t) * D + d] =
            red[0][d] + red[1][d] + red[2][d] + red[3][d] + outb[d];
      }
    }
  }
}

extern "C" void kernel_launch(void* const* d_in, const int* in_sizes, int n_in,
                              void* d_out, int out_size, void* d_ws, size_t ws_size,
                              hipStream_t stream) {
  (void)in_sizes; (void)n_in; (void)out_size; (void)ws_size;
  const float* x        = (const float*)d_in[0];
  const float* enc_Wih  = (const float*)d_in[1];
  const float* enc_Whh  = (const float*)d_in[2];
  const float* enc_b    = (const float*)d_in[3];
  const float* enc_fcW  = (const float*)d_in[4];
  const float* enc_fcb  = (const float*)d_in[5];
  const float* dec_fcW  = (const float*)d_in[6];
  const float* dec_fcb  = (const float*)d_in[7];
  const float* dec_Wih  = (const float*)d_in[8];
  const float* dec_Whh  = (const float*)d_in[9];
  const float* dec_b    = (const float*)d_in[10];
  const float* outW     = (const float*)d_in[11];
  const float* outb     = (const float*)d_in[12];

  float* ws = (float*)d_ws;
  unsigned* cnt_enc = (unsigned*)d_ws;         // ws[0]
  unsigned* cnt_dec = ((unsigned*)d_ws) + 32;  // ws[32], separate cache line

  // zero counters + both h buffers
  hipMemsetAsync(d_ws, 0, (size_t)(OFF_HBUF + 2 * H * B) * sizeof(float), stream);

  k_transpose_x<<<S, 256, 0, stream>>>(x, ws + OFF_XT);
  k_wcomb<<<G4, 256, 0, stream>>>(dec_Whh, dec_Wih, outW, ws + OFF_WCOMB);
  k_bcomb<<<G4 / 256, 256, 0, stream>>>(dec_b, dec_Wih, outb, ws + OFF_BCOMB);
  k_outwt<<<(H * D) / 256, 256, 0, stream>>>(outW, ws + OFF_OUTWT);

  k_encoder<<<NWG, TPB, 0, stream>>>(ws + OFF_XT, enc_Wih, enc_Whh, enc_b,
                                     ws + OFF_HBUF, cnt_enc);

  k_latent<<<L, 256, 0, stream>>>(ws + OFF_HBUF, enc_fcW, enc_fcb, ws + OFF_LAT);
  k_hdec<<<H, 256, 0, stream>>>(ws + OFF_LAT, dec_fcW, dec_fcb, ws + OFF_HBUF);

  k_decoder<<<NWG, TPB, 0, stream>>>(dec_Whh, dec_b, ws + OFF_WCOMB, ws + OFF_BCOMB,
                                     ws + OFF_OUTWT, outb, ws + OFF_HBUF,
                                     (float*)d_out, cnt_dec);
}

// Round 11
// 52961.267 us; speedup vs baseline: 1.8309x; 1.8309x over previous
//
#include <hip/hip_runtime.h>
#include <math.h>

#define S 512
#define B 64
#define D 64
#define H 1024
#define L 128

#define NWG 256
#define TPB 1024

// ---- workspace layout (float offsets) ----
#define OFF_CNT    0                          // 1024 uints (4KB)
#define OFF_HBUF   1024                       // 2 * H * B = 131072
#define OFF_LAT    132096                     // L * B = 8192
#define OFF_XT     140288                     // S * D * B = 2097152
#define OFF_OUTWT  2237440                    // H * D = 65536
#define OFF_BCOMB  2302976                    // 4H = 4096
#define OFF_WENC   2307072                    // H * 1088 * 4 = 4456448
#define OFF_WDEC   6763520                    // H * 1024 * 4 = 4194304
// end: 10957824 floats = 43.8 MB

__device__ __forceinline__ float sigf_(float x) { return 1.f / (1.f + __expf(-x)); }
__device__ __forceinline__ float tanhf_(float x) {
  float e = __expf(2.f * x);
  return 1.f - 2.f / (e + 1.f);
}

// Two-level grid barrier: 16 groups x 16 WGs, monotonic counters, no reset.
__device__ __forceinline__ void gridbar2(unsigned* root, unsigned* grp, int gid,
                                         unsigned step1) {
  __syncthreads();
  if (threadIdx.x == 0) {
    unsigned old = __hip_atomic_fetch_add(&grp[gid * 16], 1u, __ATOMIC_ACQ_REL,
                                          __HIP_MEMORY_SCOPE_AGENT);
    if ((old & 15u) == 15u)
      __hip_atomic_fetch_add(root, 1u, __ATOMIC_ACQ_REL, __HIP_MEMORY_SCOPE_AGENT);
    while (__hip_atomic_load(root, __ATOMIC_RELAXED, __HIP_MEMORY_SCOPE_AGENT) <
           step1 * 16u) {
      __builtin_amdgcn_s_sleep(2);
    }
    __builtin_amdgcn_fence(__ATOMIC_ACQUIRE, "agent");
  }
  __syncthreads();
}

// x [B][S][D] -> xT [S][D][B]
__global__ __launch_bounds__(256) void k_transpose_x(const float* __restrict__ x,
                                                     float* __restrict__ xT) {
  __shared__ float tile[64][65];
  const int t = blockIdx.x;
  const int c = threadIdx.x & 63;
  const int r4 = threadIdx.x >> 6;
  #pragma unroll
  for (int i = 0; i < 16; ++i) {
    int b = r4 * 16 + i;
    tile[b][c] = x[((size_t)b * S + t) * D + c];
  }
  __syncthreads();
  #pragma unroll
  for (int i = 0; i < 16; ++i) {
    int d = r4 * 16 + i;
    xT[((size_t)t * D + d) * B + c] = tile[c][d];
  }
}

// WencP[j][kk][q], kk in [0,1088): kk<1024 -> Whh[q*H+j][kk], else Wih[q*H+j][kk-1024]
__global__ __launch_bounds__(256) void k_pack_enc(const float* __restrict__ Whh,
                                                  const float* __restrict__ Wih,
                                                  float* __restrict__ WencP) {
  const int j = blockIdx.x;
  for (int c = 0; c < 5; ++c) {
    int kk = c * 256 + threadIdx.x;
    if (kk < 1088) {
      float4 v;
      float* vp = (float*)&v;
      #pragma unroll
      for (int q = 0; q < 4; ++q)
        vp[q] = (kk < 1024) ? Whh[((size_t)(q * H + j)) * H + kk]
                            : Wih[((size_t)(q * H + j)) * D + (kk - 1024)];
      *(float4*)(WencP + ((size_t)j * 1088 + kk) * 4) = v;
    }
  }
}

// WdecP[j][k][q] = dWhh[q*H+j][k] + sum_d dWih[q*H+j][d] * outW[d][k]
__global__ __launch_bounds__(256) void k_pack_dec(const float* __restrict__ dWhh,
                                                  const float* __restrict__ dWih,
                                                  const float* __restrict__ outW,
                                                  float* __restrict__ WdecP) {
  const int j = blockIdx.x;
  const int k = blockIdx.y * 256 + threadIdx.x;
  float4 v;
  float* vp = (float*)&v;
  #pragma unroll
  for (int q = 0; q < 4; ++q) {
    float acc = dWhh[((size_t)(q * H + j)) * H + k];
    const float* wih = dWih + (size_t)(q * H + j) * D;
    #pragma unroll 8
    for (int d = 0; d < D; ++d) acc = fmaf(wih[d], outW[(size_t)d * H + k], acc);
    vp[q] = acc;
  }
  *(float4*)(WdecP + ((size_t)j * 1024 + k) * 4) = v;
}

// bcomb[r] = dec_b[r] + sum_d dec_Wih[r][d]*outb[d]   (r = q*H + j)
__global__ __launch_bounds__(256) void k_bcomb(const float* __restrict__ db,
                                               const float* __restrict__ dWih,
                                               const float* __restrict__ outb,
                                               float* __restrict__ bcomb) {
  int r = blockIdx.x * 256 + threadIdx.x;
  float acc = db[r];
  #pragma unroll 8
  for (int d = 0; d < D; ++d) acc = fmaf(dWih[(size_t)r * D + d], outb[d], acc);
  bcomb[r] = acc;
}

// outW [D][H] -> outWT [H][D]
__global__ __launch_bounds__(256) void k_outwt(const float* __restrict__ outW,
                                               float* __restrict__ outWT) {
  int idx = blockIdx.x * 256 + threadIdx.x;
  int k = idx >> 6, d = idx & 63;
  outWT[idx] = outW[(size_t)d * H + k];
}

// ---------------- persistent encoder ----------------
// 256 WGs x 1024 thr. WG w owns j in {4w..4w+3}. wave wv = (p<<3)|ks:
// p: j-pair (j0 = 4w+2p), ks: K-slice (136 each of K'=1088; ks==7: 72 h + 64 x).
__global__ __launch_bounds__(TPB, 4) void k_encoder(
    const float* __restrict__ WencP, const float* __restrict__ enc_b,
    const float* __restrict__ xT, float* __restrict__ hbuf,
    unsigned* __restrict__ root, unsigned* __restrict__ grp) {
  const int tid = threadIdx.x;
  const int lane = tid & 63;
  const int wv = tid >> 6;
  const int p = wv >> 3;
  const int ks = wv & 7;
  const int w = blockIdx.x;
  const int j0 = (w << 2) + (p << 1);
  const int gid = w >> 4;

  __shared__ float red[4][8][4][64];

  float cst = 0.f;
  float bia[4];
  if (wv < 4) {
    int j = (w << 2) + wv;
    #pragma unroll
    for (int q = 0; q < 4; ++q) bia[q] = enc_b[q * H + j];
  }

  const int klen = (ks == 7) ? 72 : 136;
  const int k0 = 136 * ks;
  const float4* wp0 = (const float4*)WencP + ((size_t)j0 * 1088 + k0);
  const float4* wp1 = (const float4*)WencP + ((size_t)(j0 + 1) * 1088 + k0);

  for (int t = 0; t < S; ++t) {
    float a00 = 0, a01 = 0, a02 = 0, a03 = 0, a10 = 0, a11 = 0, a12 = 0, a13 = 0;
    if (t > 0) {
      const float* hp = hbuf + (size_t)(t & 1) * (H * B) + k0 * 64 + lane;
      #pragma unroll 4
      for (int k = 0; k < klen; ++k) {
        float hv = hp[k * 64];
        float4 w0 = wp0[k];
        float4 w1 = wp1[k];
        a00 = fmaf(w0.x, hv, a00); a01 = fmaf(w0.y, hv, a01);
        a02 = fmaf(w0.z, hv, a02); a03 = fmaf(w0.w, hv, a03);
        a10 = fmaf(w1.x, hv, a10); a11 = fmaf(w1.y, hv, a11);
        a12 = fmaf(w1.z, hv, a12); a13 = fmaf(w1.w, hv, a13);
      }
    }
    if (ks == 7) {  // x-term: weight rows 1024..1087 are Wih, contiguous
      const float* xp = xT + (size_t)t * (D * B) + lane;
      #pragma unroll 4
      for (int k = 72; k < 136; ++k) {
        float xv = xp[(k - 72) * 64];
        float4 w0 = wp0[k];
        float4 w1 = wp1[k];
        a00 = fmaf(w0.x, xv, a00); a01 = fmaf(w0.y, xv, a01);
        a02 = fmaf(w0.z, xv, a02); a03 = fmaf(w0.w, xv, a03);
        a10 = fmaf(w1.x, xv, a10); a11 = fmaf(w1.y, xv, a11);
        a12 = fmaf(w1.z, xv, a12); a13 = fmaf(w1.w, xv, a13);
      }
    }
    red[2 * p + 0][ks][0][lane] = a00; red[2 * p + 0][ks][1][lane] = a01;
    red[2 * p + 0][ks][2][lane] = a02; red[2 * p + 0][ks][3][lane] = a03;
    red[2 * p + 1][ks][0][lane] = a10; red[2 * p + 1][ks][1][lane] = a11;
    red[2 * p + 1][ks][2][lane] = a12; red[2 * p + 1][ks][3][lane] = a13;
    __syncthreads();
    if (wv < 4) {
      float g0 = bia[0], g1 = bia[1], g2 = bia[2], g3 = bia[3];
      #pragma unroll
      for (int s = 0; s < 8; ++s) {
        g0 += red[wv][s][0][lane];
        g1 += red[wv][s][1][lane];
        g2 += red[wv][s][2][lane];
        g3 += red[wv][s][3][lane];
      }
      float ii = sigf_(g0), ff = sigf_(g1), gg = tanhf_(g2), oo = sigf_(g3);
      cst = fmaf(ff, cst, ii * gg);
      float hv = oo * tanhf_(cst);
      hbuf[(size_t)((t + 1) & 1) * (H * B) + ((w << 2) + wv) * 64 + lane] = hv;
    }
    gridbar2(root, grp, gid, (unsigned)(t + 1));
  }
  // h_enc ends in hbuf[0]
}

// latent[l][b] = h_enc . enc_fcW[l] + enc_fcb[l]
__global__ __launch_bounds__(256) void k_latent(const float* __restrict__ h0,
                                                const float* __restrict__ fcW,
                                                const float* __restrict__ fcb,
                                                float* __restrict__ latT) {
  const int l = blockIdx.x;
  const int b = threadIdx.x & 63;
  const int kq = threadIdx.x >> 6;
  float acc = 0.f;
  #pragma unroll 4
  for (int kk = 0; kk < 256; ++kk) {
    int k = kq * 256 + kk;
    acc = fmaf(h0[k * B + b], fcW[(size_t)l * H + k], acc);
  }
  __shared__ float red[4][64];
  red[kq][b] = acc;
  __syncthreads();
  if (kq == 0) latT[l * B + b] = red[0][b] + red[1][b] + red[2][b] + red[3][b] + fcb[l];
}

// h_dec[j][b] -> hbuf[0]
__global__ __launch_bounds__(256) void k_hdec(const float* __restrict__ latT,
                                              const float* __restrict__ fcW,
                                              const float* __restrict__ fcb,
                                              float* __restrict__ h0) {
  const int j = blockIdx.x;
  const int b = threadIdx.x & 63;
  const int kq = threadIdx.x >> 6;
  float acc = 0.f;
  #pragma unroll
  for (int kk = 0; kk < 32; ++kk) {
    int k = kq * 32 + kk;
    acc = fmaf(latT[k * B + b], fcW[(size_t)j * L + k], acc);
  }
  __shared__ float red[4][64];
  red[kq][b] = acc;
  __syncthreads();
  if (kq == 0) h0[j * B + b] = red[0][b] + red[1][b] + red[2][b] + red[3][b] + fcb[j];
}

// ---------------- persistent decoder ----------------
// Same geometry. t==0 uses raw dec_Whh (strided uniform loads) + dec_b; t>=1 uses
// packed Wcomb + bcomb (feedback folded). WGs w<64 also do out-projection for b=w.
__global__ __launch_bounds__(TPB, 4) void k_decoder(
    const float* __restrict__ dWhh, const float* __restrict__ db,
    const float* __restrict__ WdecP, const float* __restrict__ bcomb,
    const float* __restrict__ outWT, const float* __restrict__ outb,
    float* __restrict__ hbuf, float* __restrict__ out,
    unsigned* __restrict__ root, unsigned* __restrict__ grp) {
  const int tid = threadIdx.x;
  const int lane = tid & 63;
  const int wv = tid >> 6;
  const int p = wv >> 3;
  const int ks = wv & 7;
  const int w = blockIdx.x;
  const int j0 = (w << 2) + (p << 1);
  const int gid = w >> 4;

  __shared__ float red[4][8][4][64];
  __shared__ float red2[16][64];

  float cst = 0.f;
  float b0a[4], b1a[4];
  if (wv < 4) {
    int j = (w << 2) + wv;
    #pragma unroll
    for (int q = 0; q < 4; ++q) {
      b0a[q] = db[q * H + j];
      b1a[q] = bcomb[q * H + j];
    }
  }
  const float outb_r = outb[lane];

  const int k0 = ks * 128;
  const float4* wp0 = (const float4*)WdecP + ((size_t)j0 * 1024 + k0);
  const float4* wp1 = (const float4*)WdecP + ((size_t)(j0 + 1) * 1024 + k0);
  // strided row bases for t==0 path
  const float* r0[8];
  #pragma unroll
  for (int q = 0; q < 4; ++q) {
    r0[q] = dWhh + ((size_t)(q * H + j0)) * H + k0;
    r0[4 + q] = dWhh + ((size_t)(q * H + j0 + 1)) * H + k0;
  }

  for (int t = 0; t < S; ++t) {
    const float* hc = hbuf + (size_t)(t & 1) * (H * B);

    // out-projection for step t-1 (reads same h buffer as gates)
    if (t > 0 && w < 64) {
      const float* hb = hc + (wv << 12) + w;       // k = wv*64 + kk
      const float* ob = outWT + (wv << 12) + lane;
      float acc = 0.f;
      #pragma unroll 4
      for (int kk = 0; kk < 64; ++kk) acc = fmaf(hb[kk * 64], ob[kk * 64], acc);
      red2[wv][lane] = acc;
    }

    float a00 = 0, a01 = 0, a02 = 0, a03 = 0, a10 = 0, a11 = 0, a12 = 0, a13 = 0;
    const float* hp = hc + k0 * 64 + lane;
    if (t == 0) {
      #pragma unroll 2
      for (int k = 0; k < 128; ++k) {
        float hv = hp[k * 64];
        a00 = fmaf(r0[0][k], hv, a00); a01 = fmaf(r0[1][k], hv, a01);
        a02 = fmaf(r0[2][k], hv, a02); a03 = fmaf(r0[3][k], hv, a03);
        a10 = fmaf(r0[4][k], hv, a10); a11 = fmaf(r0[5][k], hv, a11);
        a12 = fmaf(r0[6][k], hv, a12); a13 = fmaf(r0[7][k], hv, a13);
      }
    } else {
      #pragma unroll 4
      for (int k = 0; k < 128; ++k) {
        float hv = hp[k * 64];
        float4 w0 = wp0[k];
        float4 w1 = wp1[k];
        a00 = fmaf(w0.x, hv, a00); a01 = fmaf(w0.y, hv, a01);
        a02 = fmaf(w0.z, hv, a02); a03 = fmaf(w0.w, hv, a03);
        a10 = fmaf(w1.x, hv, a10); a11 = fmaf(w1.y, hv, a11);
        a12 = fmaf(w1.z, hv, a12); a13 = fmaf(w1.w, hv, a13);
      }
    }
    red[2 * p + 0][ks][0][lane] = a00; red[2 * p + 0][ks][1][lane] = a01;
    red[2 * p + 0][ks][2][lane] = a02; red[2 * p + 0][ks][3][lane] = a03;
    red[2 * p + 1][ks][0][lane] = a10; red[2 * p + 1][ks][1][lane] = a11;
    red[2 * p + 1][ks][2][lane] = a12; red[2 * p + 1][ks][3][lane] = a13;
    __syncthreads();
    if (wv < 4) {
      float g0, g1, g2, g3;
      if (t == 0) { g0 = b0a[0]; g1 = b0a[1]; g2 = b0a[2]; g3 = b0a[3]; }
      else        { g0 = b1a[0]; g1 = b1a[1]; g2 = b1a[2]; g3 = b1a[3]; }
      #pragma unroll
      for (int s = 0; s < 8; ++s) {
        g0 += red[wv][s][0][lane];
        g1 += red[wv][s][1][lane];
        g2 += red[wv][s][2][lane];
        g3 += red[wv][s][3][lane];
      }
      float ii = sigf_(g0), ff = sigf_(g1), gg = tanhf_(g2), oo = sigf_(g3);
      cst = fmaf(ff, cst, ii * gg);
      float hv = oo * tanhf_(cst);
      hbuf[(size_t)((t + 1) & 1) * (H * B) + ((w << 2) + wv) * 64 + lane] = hv;
    }
    if (t > 0 && w < 64 && wv == 4) {
      float s = outb_r;
      #pragma unroll
      for (int kq = 0; kq < 16; ++kq) s += red2[kq][lane];
      out[((size_t)w * S + (t - 1)) * D + lane] = s;
    }
    gridbar2(root, grp, gid, (unsigned)(t + 1));
  }
  // tail: out for t = 511 from h_511 in hbuf[0]
  if (w < 64) {
    const float* hb = hbuf + (wv << 12) + w;
    const float* ob = outWT + (wv << 12) + lane;
    float acc = 0.f;
    #pragma unroll 4
    for (int kk = 0; kk < 64; ++kk) acc = fmaf(hb[kk * 64], ob[kk * 64], acc);
    red2[wv][lane] = acc;
  }
  __syncthreads();
  if (w < 64 && wv == 4) {
    float s = outb_r;
    #pragma unroll
    for (int kq = 0; kq < 16; ++kq) s += red2[kq][lane];
    out[((size_t)w * S + 511) * D + lane] = s;
  }
}

extern "C" void kernel_launch(void* const* d_in, const int* in_sizes, int n_in,
                              void* d_out, int out_size, void* d_ws, size_t ws_size,
                              hipStream_t stream) {
  (void)in_sizes; (void)n_in; (void)out_size; (void)ws_size;
  const float* x       = (const float*)d_in[0];
  const float* enc_Wih = (const float*)d_in[1];
  const float* enc_Whh = (const float*)d_in[2];
  const float* enc_b   = (const float*)d_in[3];
  const float* enc_fcW = (const float*)d_in[4];
  const float* enc_fcb = (const float*)d_in[5];
  const float* dec_fcW = (const float*)d_in[6];
  const float* dec_fcb = (const float*)d_in[7];
  const float* dec_Wih = (const float*)d_in[8];
  const float* dec_Whh = (const float*)d_in[9];
  const float* dec_b   = (const float*)d_in[10];
  const float* outW    = (const float*)d_in[11];
  const float* outb    = (const float*)d_in[12];

  float* ws = (float*)d_ws;
  unsigned* cu = (unsigned*)d_ws;
  unsigned* root_enc = cu + 0;
  unsigned* grp_enc  = cu + 64;   // 16 groups * 16 uints
  unsigned* root_dec = cu + 384;
  unsigned* grp_dec  = cu + 448;

  hipMemsetAsync(d_ws, 0, 4096, stream);  // counters

  k_transpose_x<<<S, 256, 0, stream>>>(x, ws + OFF_XT);
  k_pack_enc<<<H, 256, 0, stream>>>(enc_Whh, enc_Wih, ws + OFF_WENC);
  k_pack_dec<<<dim3(H, 4), 256, 0, stream>>>(dec_Whh, dec_Wih, outW, ws + OFF_WDEC);
  k_bcomb<<<16, 256, 0, stream>>>(dec_b, dec_Wih, outb, ws + OFF_BCOMB);
  k_outwt<<<256, 256, 0, stream>>>(outW, ws + OFF_OUTWT);

  k_encoder<<<NWG, TPB, 0, stream>>>(ws + OFF_WENC, enc_b, ws + OFF_XT,
                                     ws + OFF_HBUF, root_enc, grp_enc);

  k_latent<<<L, 256, 0, stream>>>(ws + OFF_HBUF, enc_fcW, enc_fcb, ws + OFF_LAT);
  k_hdec<<<H, 256, 0, stream>>>(ws + OFF_LAT, dec_fcW, dec_fcb, ws + OFF_HBUF);

  k_decoder<<<NWG, TPB, 0, stream>>>(dec_Whh, dec_b, ws + OFF_WDEC, ws + OFF_BCOMB,
                                     ws + OFF_OUTWT, outb, ws + OFF_HBUF,
                                     (float*)d_out, root_dec, grp_dec);
}